// Round 2
// baseline (138.795 us; speedup 1.0000x reference)
//
#include <hip/hip_runtime.h>
#include <math.h>

#define NPTS 1000
#define NGRID 256
#define NEWTON_ITERS 8
#define BISECT_ITERS 40
#define EPS_D 1e-3
#define PI_D 3.14159265358979323846

// Folded polynomial coefficients, shared per block (LDS broadcast reads).
struct SC {
    double c[11];   // c_k = 4 * sum_{i+j=k} _a_i _a_j
    double pc[11];  // c_k/(k-4), pc[4]=0
    double bc[6];   // 1, b1..b5
    double dbc[5];  // i*b_i
    double S;       // sum_{k!=4} c_k/(k-4)
    double sa;      // sum a_i^2
};

__device__ inline void init_sc(const float* a, const float* b, SC* s) {
    double _a[6], _b[6];
    _a[0] = 1.0; _b[0] = 1.0;
    for (int i = 0; i < 5; ++i) { _a[i+1] = (double)a[i]; _b[i+1] = (double)b[i]; }
    double c[11];
    for (int k = 0; k < 11; ++k) c[k] = 0.0;
    for (int i = 0; i < 6; ++i)
        for (int j = 0; j < 6; ++j)
            c[i+j] += 4.0 * _a[i] * _a[j];
    double S = 0.0;
    for (int k = 0; k < 11; ++k) {
        s->c[k] = c[k];
        double p = (k == 4) ? 0.0 : (c[k] / (double)(k - 4));
        s->pc[k] = p;
        if (k != 4) S += p;
    }
    s->S = S;
    double sa = 0.0;
    for (int i = 0; i < 5; ++i) sa += (double)a[i] * (double)a[i];
    s->sa = sa;
    for (int i = 0; i < 6; ++i) s->bc[i] = _b[i];
    for (int i = 1; i < 6; ++i) s->dbc[i-1] = (double)i * _b[i];
}

// f32-faithful grids
__device__ inline double yY(int k)  { return (double)(float)(1e-3 + (double)k * (0.999 - 1e-3) / 999.0); }
__device__ inline double yYD(int k) { return (double)(float)(1e-3 + (double)k * (1.0   - 1e-3) / 999.0); }

// trapz + endpoint-extrapolation folded into per-point weights (Y grid)
__device__ inline double wY(int k) {
    double y0 = yY(0), y1 = yY(1);
    double h = y1 - y0;
    if (k == 0)   return 0.5 * (y1 - y0) + y0 + 0.5 * y0 * y0 / h;
    if (k == 1)   return 0.5 * (yY(2) - y0) - 0.5 * y0 * y0 / h;
    if (k == 999) return 0.5 * (yY(999) - yY(998)) + 0.5 * (1.0 - yY(999));
    return 0.5 * (yY(k+1) - yY(k-1));
}
// YD grid: ff = [1, I...], yf = [0, YD...]; I0 weight = 0.5*yd1
__device__ inline double wYD(int k) {
    if (k == 0)   return 0.5 * yYD(1);
    if (k == 999) return 0.5 * (yYD(999) - yYD(998));
    return 0.5 * (yYD(k+1) - yYD(k-1));
}

__device__ inline double eval_f_d(double z, double lnz, double z4, const SC* s) {
    double P = s->pc[10];
    #pragma unroll
    for (int k = 9; k >= 0; --k) P = fma(P, z, s->pc[k]);
    return s->S * z4 - P - s->c[4] * z4 * lnz + (4.0 * EPS_D) * s->sa * z4 * (1.0 - z);
}
__device__ inline double eval_Q(double z, const SC* s) {
    double Q = s->c[10];
    #pragma unroll
    for (int k = 9; k >= 0; --k) Q = fma(Q, z, s->c[k]);
    return Q;
}
__device__ inline double eval_bv(double z, const SC* s) {
    double B = s->bc[5];
    #pragma unroll
    for (int k = 4; k >= 0; --k) B = fma(B, z, s->bc[k]);
    return B;
}
__device__ inline double eval_dbv(double z, const SC* s) {
    double D = s->dbc[4];
    #pragma unroll
    for (int k = 3; k >= 0; --k) D = fma(D, z, s->dbc[k]);
    return D;
}

struct PtC { double y, u, lnu, wt; };      // per-grid-point constants (cached)
struct IterS { double zs, lnzs, zs4, inv_fs, sdf; };  // per-zs scalars

__device__ inline void iter_scalars(double zs, const SC* s, IterS* it) {
    it->zs = zs;
    it->lnzs = log(zs);
    double z2 = zs * zs;
    it->zs4 = z2 * z2;
    double f = eval_f_d(zs, it->lnzs, it->zs4, s);
    double Q = eval_Q(zs, s);
    double dfs = (4.0 * f - Q) / zs - (4.0 * EPS_D) * s->sa * it->zs4;
    it->inv_fs = 1.0 / f;
    it->sdf = zs * dfs / f;   // zs*dfs/fs
}

// Combined L / dL integrands at point p for scalars is. Unused path is DCE'd.
template <bool NL, bool ND>
__device__ inline void integrands(const PtC& p, const IterS& is, const SC* s,
                                  double& IL, double& ID) {
    double u = p.u;
    double w4 = u * u; w4 = w4 * w4;
    double z   = is.zs * u;
    double lnz = is.lnzs + p.lnu;
    double z4  = is.zs4 * w4;
    double f = eval_f_d(z, lnz, z4, s);
    double bv = eval_bv(z, s);
    double inv_f = 1.0 / f;
    double g = bv * bv * inv_f;
    double sqrtg = sqrt(g);
    double fofs = f * is.inv_fs;
    if (NL) {
        IL = sqrtg * p.y / sqrt(fofs / w4 - 1.0);
    }
    if (ND) {
        double Q = eval_Q(z, s);
        double df = (4.0 * f - Q) / z - (4.0 * EPS_D) * s->sa * z4;
        double dbv = eval_dbv(z, s);
        double r4 = 1.0 / w4;                  // zs^4/z^4
        double A = r4 * fofs;
        double t = z * (2.0 * dbv / bv - df * inv_f);   // z*dg/g
        double i1 = A * (is.sdf + 2.0 + t) - r4 * z * df * is.inv_fs - 2.0 - t;
        double Am1 = A - 1.0;
        ID = i1 * 2.0 * sqrt(1.0 - u) * sqrtg / (Am1 * sqrt(Am1));
    }
}

// deterministic block reduction of 2 doubles (256 threads = 4 waves)
__device__ inline void block_reduce2(double& sx, double& sy, double2* lds, int tid) {
    #pragma unroll
    for (int off = 32; off > 0; off >>= 1) {
        sx += __shfl_xor(sx, off);
        sy += __shfl_xor(sy, off);
    }
    int wid = tid >> 6;
    if ((tid & 63) == 0) lds[wid] = make_double2(sx, sy);
    __syncthreads();
    double rx = 0.0, ry = 0.0;
    #pragma unroll
    for (int w = 0; w < 4; ++w) { rx += lds[w].x; ry += lds[w].y; }
    __syncthreads();   // lds reusable next call
    sx = rx; sy = ry;
}

__device__ inline void load_points(int tid, PtC* p) {
    #pragma unroll
    for (int j = 0; j < 4; ++j) {
        int k = tid + j * 256;
        int kk = (k < NPTS) ? k : (NPTS - 1);
        double y = yY(kk);
        double u = (1.0 - y) * (1.0 + y);
        p[j].y = y;
        p[j].u = u;
        p[j].lnu = log(u);
        p[j].wt = (k < NPTS) ? wY(kk) : 0.0;
    }
}

// ---------------- Kernel 1: bisection for zs_max (single block) ----------------
__global__ __launch_bounds__(256) void k_bisect(const float* a, const float* b, double* ws) {
    __shared__ SC sc;
    __shared__ double2 red[4];
    int tid = threadIdx.x;
    if (tid == 0) init_sc(a, b, &sc);
    __syncthreads();
    PtC p[4];
    load_points(tid, p);

    float lo = 1e-3f, hi = 0.999f;
    for (int it = 0; it < BISECT_ITERS; ++it) {
        float mid = 0.5f * (lo + hi);
        IterS is;
        iter_scalars((double)mid, &sc, &is);
        double sD = 0.0, dummy = 0.0;
        #pragma unroll
        for (int j = 0; j < 4; ++j) {
            double IL, ID;
            integrands<false, true>(p[j], is, &sc, IL, ID);
            sD += p[j].wt * ID;
        }
        block_reduce2(sD, dummy, red, tid);
        if (sD < 0.0) hi = mid; else lo = mid;   // sign(dL) = sign(sum)
    }
    if (tid == 0) ws[0] = (double)(0.5f * (lo + hi));
}

// ---------------- Kernel 2: Lg over the zs grid ----------------
__global__ __launch_bounds__(256) void k_grid(const float* a, const float* b, double* ws) {
    __shared__ SC sc;
    __shared__ double2 red[4];
    int tid = threadIdx.x, blk = blockIdx.x;
    if (tid == 0) init_sc(a, b, &sc);
    __syncthreads();
    PtC p[4];
    load_points(tid, p);

    double zmax = ws[0];
    double t = 0.05 + (double)blk * (0.999 - 0.05) / 255.0;
    double zs = zmax * (double)(float)t;

    IterS is;
    iter_scalars(zs, &sc, &is);
    double sL = 0.0, dummy = 0.0;
    #pragma unroll
    for (int j = 0; j < 4; ++j) {
        double IL, ID;
        integrands<true, false>(p[j], is, &sc, IL, ID);
        sL += p[j].wt * IL;
    }
    block_reduce2(sL, dummy, red, tid);
    if (tid == 0) {
        ws[1 + blk] = 4.0 * zs * sL / PI_D;   // Lg
        ws[1 + NGRID + blk] = zs;             // zs_grid
    }
}

// ---------------- Kernel 3: argmin init + Newton + Vc/Vd ----------------
__global__ __launch_bounds__(256) void k_newton(const float* Ls, const float* a, const float* b,
                                                const float* logcoef, const double* ws,
                                                float* out, int out_size, int B) {
    __shared__ SC sc;
    __shared__ double2 red[4];
    __shared__ double wv[4];
    __shared__ int wi[4];
    int tid = threadIdx.x, blk = blockIdx.x;
    if (tid == 0) init_sc(a, b, &sc);
    __syncthreads();

    double Lt = (double)Ls[blk];

    // argmin |Lg - L| (first-min tie-break, like jnp.argmin)
    double v = fabs(ws[1 + tid] - Lt);
    int idx = tid;
    #pragma unroll
    for (int off = 32; off > 0; off >>= 1) {
        double ov = __shfl_xor(v, off);
        int oi = __shfl_xor(idx, off);
        if (ov < v || (ov == v && oi < idx)) { v = ov; idx = oi; }
    }
    if ((tid & 63) == 0) { wv[tid >> 6] = v; wi[tid >> 6] = idx; }
    __syncthreads();
    v = wv[0]; idx = wi[0];
    #pragma unroll
    for (int w = 1; w < 4; ++w) {
        if (wv[w] < v || (wv[w] == v && wi[w] < idx)) { v = wv[w]; idx = wi[w]; }
    }
    double zs = ws[1 + NGRID + idx];

    PtC p[4];
    load_points(tid, p);

    // Newton (8 fixed iterations; combined L + dL pass)
    for (int itn = 0; itn < NEWTON_ITERS; ++itn) {
        IterS is;
        iter_scalars(zs, &sc, &is);
        double sL = 0.0, sD = 0.0;
        #pragma unroll
        for (int j = 0; j < 4; ++j) {
            double IL, ID;
            integrands<true, true>(p[j], is, &sc, IL, ID);
            sL += p[j].wt * IL;
            sD += p[j].wt * ID;
        }
        block_reduce2(sL, sD, red, tid);
        double L_  = 4.0 * zs * sL / PI_D;
        double dL  = sD / PI_D;
        zs = zs - (L_ - Lt) / dL;
    }
    // reference: zs = complex(real, abs(imag)); real path -> unchanged

    // Vc (Y grid) + Vd (YD grid), fused pass
    IterS is;
    iter_scalars(zs, &sc, &is);
    double elc = exp((double)logcoef[0]);
    double sVc = 0.0, sVd = 0.0;
    #pragma unroll
    for (int j = 0; j < 4; ++j) {
        int k = tid + j * 256;
        bool ok = (k < NPTS);
        int kk = ok ? k : (NPTS - 1);
        {   // connected: z = zs*(1-y)(1+y)
            double u = p[j].u;
            double w2 = u * u;
            double z   = is.zs * u;
            double lnz = is.lnzs + p[j].lnu;
            double z4  = is.zs4 * w2 * w2;
            double f = eval_f_d(z, lnz, z4, &sc);
            double bv = eval_bv(z, &sc);
            double g = bv * bv / f;
            double fg = f * g;
            double fofs = f * is.inv_fs;
            double arg = 1.0 - w2 * w2 / fofs;
            double Ic = sqrt(fg) / w2 * (1.0 / sqrt(arg) - 1.0) * p[j].y;
            sVc += p[j].wt * Ic;
        }
        {   // disconnected: z = 1-(1-zs)*yd
            double yd = yYD(kk);
            double z = 1.0 - (1.0 - zs) * yd;
            double lnz = log(z);
            double z2 = z * z, z4 = z2 * z2;
            double f = eval_f_d(z, lnz, z4, &sc);
            double bv = eval_bv(z, &sc);
            double fg = f * (bv * bv / f);
            double Id = sqrt(fg) / z2;
            sVd += (ok ? wYD(kk) : 0.0) * Id;
        }
    }
    block_reduce2(sVc, sVd, red, tid);
    double Vc = elc * PI_D * 4.0 * sVc / zs;
    double Vd = elc * PI_D * 2.0 * (1.0 - zs) * (0.5 * yYD(0) + sVd);
    double outv = Vc - Vd;

    if (tid == 0) {
        if (out_size >= 2 * B) {   // complex64 layout: interleaved re, im
            out[2 * blk]     = (float)outv;
            out[2 * blk + 1] = 0.0f;
        } else {
            out[blk] = (float)outv;
        }
    }
}

extern "C" void kernel_launch(void* const* d_in, const int* in_sizes, int n_in,
                              void* d_out, int out_size, void* d_ws, size_t ws_size,
                              hipStream_t stream) {
    const float* Ls = (const float*)d_in[0];
    const float* a  = (const float*)d_in[1];
    const float* b  = (const float*)d_in[2];
    const float* lc = (const float*)d_in[3];
    double* ws = (double*)d_ws;
    int B = in_sizes[0];

    hipLaunchKernelGGL(k_bisect, dim3(1), dim3(256), 0, stream, a, b, ws);
    hipLaunchKernelGGL(k_grid, dim3(NGRID), dim3(256), 0, stream, a, b, ws);
    hipLaunchKernelGGL(k_newton, dim3(B), dim3(256), 0, stream,
                       Ls, a, b, lc, ws, (float*)d_out, out_size, B);
}

// Round 8
// 74.595 us; speedup vs baseline: 1.8607x; 1.8607x over previous
//
#include <hip/hip_runtime.h>
#include <math.h>

#define NPTS 1000
#define NGRID 256
#define NSCAN 1024
#define NEWTON_ITERS 8
#define EPS_D 1e-3
#define PI_D 3.14159265358979323846

// ws layout (doubles): [0..NSCAN-1] = dL at scan points; [NSCAN..NSCAN+255] = Lg;
// [NSCAN+256..NSCAN+511] = zs_grid
#define WS_LG   NSCAN
#define WS_ZS   (NSCAN + NGRID)

// Folded polynomial coefficients, shared per block.
struct SC {
    double c[11];   // c_k = 4 * sum_{i+j=k} _a_i _a_j
    double pc[11];  // c_k/(k-4), pc[4]=0
    double bc[6];   // 1, b1..b5
    double dbc[5];  // i*b_i
    double S;       // sum_{k!=4} c_k/(k-4)
    double sa;      // sum a_i^2
};

__device__ inline void init_sc(const float* a, const float* b, SC* s) {
    double _a[6], _b[6];
    _a[0] = 1.0; _b[0] = 1.0;
    for (int i = 0; i < 5; ++i) { _a[i+1] = (double)a[i]; _b[i+1] = (double)b[i]; }
    double c[11];
    for (int k = 0; k < 11; ++k) c[k] = 0.0;
    for (int i = 0; i < 6; ++i)
        for (int j = 0; j < 6; ++j)
            c[i+j] += 4.0 * _a[i] * _a[j];
    double S = 0.0;
    for (int k = 0; k < 11; ++k) {
        s->c[k] = c[k];
        double p = (k == 4) ? 0.0 : (c[k] / (double)(k - 4));
        s->pc[k] = p;
        if (k != 4) S += p;
    }
    s->S = S;
    double sa = 0.0;
    for (int i = 0; i < 5; ++i) sa += (double)a[i] * (double)a[i];
    s->sa = sa;
    for (int i = 0; i < 6; ++i) s->bc[i] = _b[i];
    for (int i = 1; i < 6; ++i) s->dbc[i-1] = (double)i * _b[i];
}

// f32-faithful grids
__device__ inline double yY(int k)  { return (double)(float)(1e-3 + (double)k * (0.999 - 1e-3) / 999.0); }
__device__ inline double yYD(int k) { return (double)(float)(1e-3 + (double)k * (1.0   - 1e-3) / 999.0); }

// trapz + endpoint-extrapolation folded into per-point weights (Y grid)
__device__ inline double wY(int k) {
    double y0 = yY(0), y1 = yY(1);
    double h = y1 - y0;
    if (k == 0)   return 0.5 * (y1 - y0) + y0 + 0.5 * y0 * y0 / h;
    if (k == 1)   return 0.5 * (yY(2) - y0) - 0.5 * y0 * y0 / h;
    if (k == 999) return 0.5 * (yY(999) - yY(998)) + 0.5 * (1.0 - yY(999));
    return 0.5 * (yY(k+1) - yY(k-1));
}
// YD grid: ff = [1, I...], yf = [0, YD...]; I0 weight = 0.5*yd1
__device__ inline double wYD(int k) {
    if (k == 0)   return 0.5 * yYD(1);
    if (k == 999) return 0.5 * (yYD(999) - yYD(998));
    return 0.5 * (yYD(k+1) - yYD(k-1));
}

__device__ inline double eval_f_d(double z, double lnz, double z4, const SC* s) {
    double P = s->pc[10];
    #pragma unroll
    for (int k = 9; k >= 0; --k) P = fma(P, z, s->pc[k]);
    return s->S * z4 - P - s->c[4] * z4 * lnz + (4.0 * EPS_D) * s->sa * z4 * (1.0 - z);
}
__device__ inline double eval_Q(double z, const SC* s) {
    double Q = s->c[10];
    #pragma unroll
    for (int k = 9; k >= 0; --k) Q = fma(Q, z, s->c[k]);
    return Q;
}
__device__ inline double eval_bv(double z, const SC* s) {
    double B = s->bc[5];
    #pragma unroll
    for (int k = 4; k >= 0; --k) B = fma(B, z, s->bc[k]);
    return B;
}
__device__ inline double eval_dbv(double z, const SC* s) {
    double D = s->dbc[4];
    #pragma unroll
    for (int k = 3; k >= 0; --k) D = fma(D, z, s->dbc[k]);
    return D;
}

struct PtC { double y, u, lnu, wt, inv_u; };
struct IterS { double zs, lnzs, zs4, inv_fs, inv_zs, sdf; };

__device__ inline void iter_scalars(double zs, const SC* s, IterS* it) {
    it->zs = zs;
    it->lnzs = log(zs);
    double z2 = zs * zs;
    it->zs4 = z2 * z2;
    it->inv_zs = 1.0 / zs;
    double f = eval_f_d(zs, it->lnzs, it->zs4, s);
    double Q = eval_Q(zs, s);
    double dfs = (4.0 * f - Q) * it->inv_zs - (4.0 * EPS_D) * s->sa * it->zs4;
    it->inv_fs = 1.0 / f;
    it->sdf = zs * dfs * it->inv_fs;   // zs*dfs/fs
}

// Combined L / dL integrands. sqrt(1-z/zs)=y; 1/(Am1*sqrt(Am1))=rsqrt(Am1)^3.
template <bool NL, bool ND>
__device__ inline void integrands(const PtC& p, const IterS& is, const SC* s,
                                  double& IL, double& ID) {
    double u = p.u;
    double w2 = u * u, w4 = w2 * w2;
    double z   = is.zs * u;
    double lnz = is.lnzs + p.lnu;
    double z4  = is.zs4 * w4;
    double f = eval_f_d(z, lnz, z4, s);
    double bv = eval_bv(z, s);
    double inv_f = 1.0 / f;
    double sqrtg = fabs(bv) * rsqrt(f);
    double fofs = f * is.inv_fs;
    double iu2 = p.inv_u * p.inv_u;
    double r4 = iu2 * iu2;               // zs^4/z^4
    double A = fofs * r4;
    double r = rsqrt(A - 1.0);
    if (NL) {
        IL = sqrtg * p.y * r;
    }
    if (ND) {
        double Q = eval_Q(z, s);
        double inv_z = is.inv_zs * p.inv_u;
        double df = (4.0 * f - Q) * inv_z - (4.0 * EPS_D) * s->sa * z4;
        double dbv = eval_dbv(z, s);
        double t = z * (2.0 * dbv / bv - df * inv_f);   // z*dg/g
        double i1 = A * (is.sdf + 2.0 + t) - r4 * z * df * is.inv_fs - 2.0 - t;
        ID = i1 * 2.0 * p.y * sqrtg * (r * r * r);
    }
}

// deterministic block reduction of 2 doubles (512 threads = 8 waves)
__device__ inline void block_reduce2(double& sx, double& sy, double2* lds, int tid) {
    #pragma unroll
    for (int off = 32; off > 0; off >>= 1) {
        sx += __shfl_xor(sx, off);
        sy += __shfl_xor(sy, off);
    }
    int wid = tid >> 6;
    if ((tid & 63) == 0) lds[wid] = make_double2(sx, sy);
    __syncthreads();
    double rx = 0.0, ry = 0.0;
    #pragma unroll
    for (int w = 0; w < 8; ++w) { rx += lds[w].x; ry += lds[w].y; }
    __syncthreads();
    sx = rx; sy = ry;
}

__device__ inline int block_min_int(int v, int* lds, int tid) {
    #pragma unroll
    for (int off = 32; off > 0; off >>= 1) {
        int o = __shfl_xor(v, off);
        v = (o < v) ? o : v;
    }
    if ((tid & 63) == 0) lds[tid >> 6] = v;
    __syncthreads();
    int r = lds[0];
    #pragma unroll
    for (int w = 1; w < 8; ++w) r = (lds[w] < r) ? lds[w] : r;
    __syncthreads();
    return r;
}

__device__ inline void load_points(int tid, PtC* p) {
    #pragma unroll
    for (int j = 0; j < 2; ++j) {
        int k = tid + j * 512;
        int kk = (k < NPTS) ? k : (NPTS - 1);
        double y = yY(kk);
        double u = (1.0 - y) * (1.0 + y);
        p[j].y = y;
        p[j].u = u;
        p[j].lnu = log(u);
        p[j].inv_u = 1.0 / u;
        p[j].wt = (k < NPTS) ? wY(kk) : 0.0;
    }
}

__device__ inline double scan_zs(int i) {
    return 1e-3 + (double)i * (0.999 - 1e-3) / (double)(NSCAN - 1);
}

// ---------------- Kernel 1: parallel dL sign-scan (replaces serial bisection) ----------------
__global__ __launch_bounds__(512) void k_scan(const float* a, const float* b, double* ws) {
    __shared__ SC sc;
    __shared__ double2 red[8];
    int tid = threadIdx.x, blk = blockIdx.x;
    if (tid == 0) init_sc(a, b, &sc);
    __syncthreads();
    PtC p[2];
    load_points(tid, p);

    IterS is;
    iter_scalars(scan_zs(blk), &sc, &is);
    double sD = 0.0, dummy = 0.0;
    #pragma unroll
    for (int j = 0; j < 2; ++j) {
        double IL, ID;
        integrands<false, true>(p[j], is, &sc, IL, ID);
        sD += p[j].wt * ID;
    }
    block_reduce2(sD, dummy, red, tid);
    if (tid == 0) ws[blk] = sD;
}

// ---------------- Kernel 2: Lg over the zs grid (derives zs_max from scan) ----------------
__global__ __launch_bounds__(512) void k_grid(const float* a, const float* b, double* ws) {
    __shared__ SC sc;
    __shared__ double2 red[8];
    __shared__ int ired[8];
    int tid = threadIdx.x, blk = blockIdx.x;
    if (tid == 0) init_sc(a, b, &sc);
    __syncthreads();

    // first index with dL < 0
    int cand = 1 << 30;
    #pragma unroll
    for (int j = 0; j < 2; ++j) {
        int i = tid + j * 512;
        if (ws[i] < 0.0) cand = (i < cand) ? i : cand;
    }
    int idx = block_min_int(cand, ired, tid);
    double zmax;
    if (idx >= NSCAN) zmax = 0.999;
    else if (idx == 0) zmax = 1e-3;
    else zmax = 0.5 * (scan_zs(idx - 1) + scan_zs(idx));

    PtC p[2];
    load_points(tid, p);

    double t = 0.05 + (double)blk * (0.999 - 0.05) / 255.0;
    double zs = zmax * (double)(float)t;

    IterS is;
    iter_scalars(zs, &sc, &is);
    double sL = 0.0, dummy = 0.0;
    #pragma unroll
    for (int j = 0; j < 2; ++j) {
        double IL, ID;
        integrands<true, false>(p[j], is, &sc, IL, ID);
        sL += p[j].wt * IL;
    }
    block_reduce2(sL, dummy, red, tid);
    if (tid == 0) {
        ws[WS_LG + blk] = 4.0 * zs * sL / PI_D;   // Lg
        ws[WS_ZS + blk] = zs;                     // zs_grid
    }
}

// ---------------- Kernel 3: argmin init + Newton + Vc/Vd ----------------
__global__ __launch_bounds__(512) void k_newton(const float* Ls, const float* a, const float* b,
                                                const float* logcoef, const double* ws,
                                                float* out, int out_size, int B) {
    __shared__ SC sc;
    __shared__ double2 red[8];
    __shared__ double wv[8];
    __shared__ int wi[8];
    int tid = threadIdx.x, blk = blockIdx.x;
    if (tid == 0) init_sc(a, b, &sc);
    __syncthreads();

    double Lt = (double)Ls[blk];

    // argmin |Lg - L| over 256 grid entries (first-min tie-break)
    double v = (tid < NGRID) ? fabs(ws[WS_LG + tid] - Lt) : 1e300;
    int idx = (tid < NGRID) ? tid : (1 << 30);
    #pragma unroll
    for (int off = 32; off > 0; off >>= 1) {
        double ov = __shfl_xor(v, off);
        int oi = __shfl_xor(idx, off);
        if (ov < v || (ov == v && oi < idx)) { v = ov; idx = oi; }
    }
    if ((tid & 63) == 0) { wv[tid >> 6] = v; wi[tid >> 6] = idx; }
    __syncthreads();
    v = wv[0]; idx = wi[0];
    #pragma unroll
    for (int w = 1; w < 8; ++w) {
        if (wv[w] < v || (wv[w] == v && wi[w] < idx)) { v = wv[w]; idx = wi[w]; }
    }
    double zs = ws[WS_ZS + idx];

    PtC p[2];
    load_points(tid, p);

    // Newton (8 fixed iterations; combined L + dL pass)
    for (int itn = 0; itn < NEWTON_ITERS; ++itn) {
        IterS is;
        iter_scalars(zs, &sc, &is);
        double sL = 0.0, sD = 0.0;
        #pragma unroll
        for (int j = 0; j < 2; ++j) {
            double IL, ID;
            integrands<true, true>(p[j], is, &sc, IL, ID);
            sL += p[j].wt * IL;
            sD += p[j].wt * ID;
        }
        block_reduce2(sL, sD, red, tid);
        double L_  = 4.0 * zs * sL / PI_D;
        double dL  = sD / PI_D;
        zs = zs - (L_ - Lt) / dL;
    }

    // Vc (Y grid) + Vd (YD grid), fused.
    // sqrt(f*g) = |bv| exactly (g = bv^2/f), so Vd needs no f/log at all.
    IterS is;
    iter_scalars(zs, &sc, &is);
    double elc = exp((double)logcoef[0]);
    double sVc = 0.0, sVd = 0.0;
    #pragma unroll
    for (int j = 0; j < 2; ++j) {
        int k = tid + j * 512;
        bool ok = (k < NPTS);
        int kk = ok ? k : (NPTS - 1);
        {   // connected: z = zs*(1-y)(1+y)
            double u = p[j].u;
            double w2 = u * u, w4 = w2 * w2;
            double z   = is.zs * u;
            double lnz = is.lnzs + p[j].lnu;
            double z4  = is.zs4 * w4;
            double f = eval_f_d(z, lnz, z4, &sc);
            double bv = eval_bv(z, &sc);
            double inv_f = 1.0 / f;
            double iu2 = p[j].inv_u * p[j].inv_u;
            double arg = 1.0 - w4 * (1.0 / is.inv_fs) * inv_f;  // 1 - w4*fs/f
            double Ic = fabs(bv) * (rsqrt(arg) - 1.0) * p[j].y * iu2;
            sVc += p[j].wt * Ic;
        }
        {   // disconnected: z = 1-(1-zs)*yd ; integrand = |bv(z)|/z^2
            double yd = yYD(kk);
            double z = 1.0 - (1.0 - zs) * yd;
            double bv = eval_bv(z, &sc);
            double Id = fabs(bv) / (z * z);
            sVd += (ok ? wYD(kk) : 0.0) * Id;
        }
    }
    block_reduce2(sVc, sVd, red, tid);
    double Vc = elc * PI_D * 4.0 * sVc * is.inv_zs;
    double Vd = elc * PI_D * 2.0 * (1.0 - zs) * (0.5 * yYD(0) + sVd);
    double outv = Vc - Vd;

    if (tid == 0) {
        if (out_size >= 2 * B) {   // complex64 layout: interleaved re, im
            out[2 * blk]     = (float)outv;
            out[2 * blk + 1] = 0.0f;
        } else {
            out[blk] = (float)outv;
        }
    }
}

extern "C" void kernel_launch(void* const* d_in, const int* in_sizes, int n_in,
                              void* d_out, int out_size, void* d_ws, size_t ws_size,
                              hipStream_t stream) {
    const float* Ls = (const float*)d_in[0];
    const float* a  = (const float*)d_in[1];
    const float* b  = (const float*)d_in[2];
    const float* lc = (const float*)d_in[3];
    double* ws = (double*)d_ws;
    int B = in_sizes[0];

    hipLaunchKernelGGL(k_scan, dim3(NSCAN), dim3(512), 0, stream, a, b, ws);
    hipLaunchKernelGGL(k_grid, dim3(NGRID), dim3(512), 0, stream, a, b, ws);
    hipLaunchKernelGGL(k_newton, dim3(B), dim3(512), 0, stream,
                       Ls, a, b, lc, ws, (float*)d_out, out_size, B);
}

// Round 10
// 47.051 us; speedup vs baseline: 2.9499x; 1.5854x over previous
//
#include <hip/hip_runtime.h>
#include <math.h>

#define NPTS 1000
#define NGRID 256
#define NSCAN 1024
#define NEWTON_ITERS 6
#define PI_D 3.14159265358979323846

// ws layout (doubles): [0..NSCAN-1] = dL at scan points; [NSCAN..+255] = Lg;
// [NSCAN+256..+511] = zs_grid
#define WS_LG   NSCAN
#define WS_ZS   (NSCAN + NGRID)

// Folded polynomial coefficients — per-thread registers (f32), init in f64.
struct SCf {
    float c[11];   // c_k = 4 * sum_{i+j=k} _a_i _a_j
    float pc[11];  // c_k/(k-4), pc[4]=0
    float bc[6];   // 1, b1..b5
    float dbc[5];  // i*b_i
    float S;       // sum_{k!=4} c_k/(k-4)
    float sa;      // sum a_i^2
};

__device__ inline void init_scf(const float* a, const float* b, SCf& s) {
    double _a[6], _b[6];
    _a[0] = 1.0; _b[0] = 1.0;
    #pragma unroll
    for (int i = 0; i < 5; ++i) { _a[i+1] = (double)a[i]; _b[i+1] = (double)b[i]; }
    double c[11];
    #pragma unroll
    for (int k = 0; k < 11; ++k) c[k] = 0.0;
    #pragma unroll
    for (int i = 0; i < 6; ++i)
        #pragma unroll
        for (int j = 0; j < 6; ++j)
            c[i+j] += 4.0 * _a[i] * _a[j];
    double S = 0.0;
    #pragma unroll
    for (int k = 0; k < 11; ++k) {
        s.c[k] = (float)c[k];
        double p = (k == 4) ? 0.0 : (c[k] / (double)(k - 4));
        s.pc[k] = (float)p;
        if (k != 4) S += p;
    }
    s.S = (float)S;
    double sa = 0.0;
    #pragma unroll
    for (int i = 0; i < 5; ++i) sa += (double)a[i] * (double)a[i];
    s.sa = (float)sa;
    #pragma unroll
    for (int i = 0; i < 6; ++i) s.bc[i] = (float)_b[i];
    #pragma unroll
    for (int i = 1; i < 6; ++i) s.dbc[i-1] = (float)((double)i * _b[i]);
}

// f32-faithful grids (setup only, f64)
__device__ inline double yY(int k)  { return (double)(float)(1e-3 + (double)k * (0.999 - 1e-3) / 999.0); }
__device__ inline double yYD(int k) { return (double)(float)(1e-3 + (double)k * (1.0   - 1e-3) / 999.0); }

__device__ inline double wY(int k) {
    double y0 = yY(0), y1 = yY(1);
    double h = y1 - y0;
    if (k == 0)   return 0.5 * (y1 - y0) + y0 + 0.5 * y0 * y0 / h;
    if (k == 1)   return 0.5 * (yY(2) - y0) - 0.5 * y0 * y0 / h;
    if (k == 999) return 0.5 * (yY(999) - yY(998)) + 0.5 * (1.0 - yY(999));
    return 0.5 * (yY(k+1) - yY(k-1));
}
__device__ inline double wYD(int k) {
    if (k == 0)   return 0.5 * yYD(1);
    if (k == 999) return 0.5 * (yYD(999) - yYD(998));
    return 0.5 * (yYD(k+1) - yYD(k-1));
}

__device__ inline float eval_f_f(float z, float lnz, float z4, const SCf& s) {
    float P = s.pc[10];
    #pragma unroll
    for (int k = 9; k >= 0; --k) P = fmaf(P, z, s.pc[k]);
    return s.S * z4 - P - s.c[4] * z4 * lnz + 0.004f * s.sa * z4 * (1.0f - z);
}
__device__ inline float eval_Q_f(float z, const SCf& s) {
    float Q = s.c[10];
    #pragma unroll
    for (int k = 9; k >= 0; --k) Q = fmaf(Q, z, s.c[k]);
    return Q;
}
__device__ inline float eval_bv_f(float z, const SCf& s) {
    float B = s.bc[5];
    #pragma unroll
    for (int k = 4; k >= 0; --k) B = fmaf(B, z, s.bc[k]);
    return B;
}
__device__ inline float eval_dbv_f(float z, const SCf& s) {
    float D = s.dbc[4];
    #pragma unroll
    for (int k = 3; k >= 0; --k) D = fmaf(D, z, s.dbc[k]);
    return D;
}

struct PtCf { float y, u, lnu, wt, inv_u; };
struct ItSf { float zs, lnzs, zs4, fs, inv_fs, inv_zs, sdf; };

__device__ inline void iter_scalars_f(float zs, const SCf& s, ItSf& it) {
    it.zs = zs;
    it.lnzs = __logf(zs);
    float z2 = zs * zs;
    it.zs4 = z2 * z2;
    it.inv_zs = __fdividef(1.0f, zs);
    float f = eval_f_f(zs, it.lnzs, it.zs4, s);
    float Q = eval_Q_f(zs, s);
    float dfs = (4.0f * f - Q) * it.inv_zs - 0.004f * s.sa * it.zs4;
    it.fs = f;
    it.inv_fs = __fdividef(1.0f, f);
    it.sdf = zs * dfs * it.inv_fs;   // zs*dfs/fs
}

// Combined L / dL integrands (f32). sqrt(1-z/zs)=y; 1/(Am1^1.5)=rsqrt^3.
template <bool NL, bool ND>
__device__ inline void integrands_f(const PtCf& p, const ItSf& is, const SCf& s,
                                    float& IL, float& ID) {
    float u = p.u;
    float w2 = u * u, w4 = w2 * w2;
    float z   = is.zs * u;
    float lnz = is.lnzs + p.lnu;
    float z4  = is.zs4 * w4;
    float f = eval_f_f(z, lnz, z4, s);
    float bv = eval_bv_f(z, s);
    float inv_f = __fdividef(1.0f, f);
    float sqrtg = fabsf(bv) * rsqrtf(f);
    float fofs = f * is.inv_fs;
    float iu2 = p.inv_u * p.inv_u;
    float r4 = iu2 * iu2;                // zs^4/z^4
    float A = fofs * r4;
    float r = rsqrtf(A - 1.0f);
    if (NL) {
        IL = sqrtg * p.y * r;
    }
    if (ND) {
        float Q = eval_Q_f(z, s);
        float inv_z = is.inv_zs * p.inv_u;
        float df = (4.0f * f - Q) * inv_z - 0.004f * s.sa * z4;
        float dbv = eval_dbv_f(z, s);
        float t = z * (2.0f * __fdividef(dbv, bv) - df * inv_f);   // z*dg/g
        float i1 = A * (is.sdf + 2.0f + t) - r4 * z * df * is.inv_fs - 2.0f - t;
        ID = i1 * 2.0f * p.y * sqrtg * (r * r * r);
    }
}

// deterministic block reduction of 2 doubles (512 threads = 8 waves)
__device__ inline void block_reduce2(double& sx, double& sy, double2* lds, int tid) {
    #pragma unroll
    for (int off = 32; off > 0; off >>= 1) {
        sx += __shfl_xor(sx, off);
        sy += __shfl_xor(sy, off);
    }
    int wid = tid >> 6;
    if ((tid & 63) == 0) lds[wid] = make_double2(sx, sy);
    __syncthreads();
    double rx = 0.0, ry = 0.0;
    #pragma unroll
    for (int w = 0; w < 8; ++w) { rx += lds[w].x; ry += lds[w].y; }
    __syncthreads();
    sx = rx; sy = ry;
}

__device__ inline int block_min_int(int v, int* lds, int tid) {
    #pragma unroll
    for (int off = 32; off > 0; off >>= 1) {
        int o = __shfl_xor(v, off);
        v = (o < v) ? o : v;
    }
    if ((tid & 63) == 0) lds[tid >> 6] = v;
    __syncthreads();
    int r = lds[0];
    #pragma unroll
    for (int w = 1; w < 8; ++w) r = (lds[w] < r) ? lds[w] : r;
    __syncthreads();
    return r;
}

__device__ inline void load_points_f(int tid, PtCf* p) {
    #pragma unroll
    for (int j = 0; j < 2; ++j) {
        int k = tid + j * 512;
        int kk = (k < NPTS) ? k : (NPTS - 1);
        double y = yY(kk);
        double u = (1.0 - y) * (1.0 + y);
        p[j].y = (float)y;
        p[j].u = (float)u;
        p[j].lnu = (float)log(u);
        p[j].inv_u = (float)(1.0 / u);
        p[j].wt = (float)((k < NPTS) ? wY(kk) : 0.0);
    }
}

__device__ inline double scan_zs(int i) {
    return 1e-3 + (double)i * (0.999 - 1e-3) / (double)(NSCAN - 1);
}

// ---------------- Kernel 1: parallel dL sign-scan ----------------
__global__ __launch_bounds__(512, 4) void k_scan(const float* a, const float* b, double* ws) {
    __shared__ double2 red[8];
    int tid = threadIdx.x, blk = blockIdx.x;
    SCf sc;
    init_scf(a, b, sc);
    PtCf p[2];
    load_points_f(tid, p);

    ItSf is;
    iter_scalars_f((float)scan_zs(blk), sc, is);
    float sDf = 0.0f;
    #pragma unroll
    for (int j = 0; j < 2; ++j) {
        float IL, ID;
        integrands_f<false, true>(p[j], is, sc, IL, ID);
        sDf = fmaf(p[j].wt, ID, sDf);
    }
    double sD = (double)sDf, dummy = 0.0;
    block_reduce2(sD, dummy, red, tid);
    if (tid == 0) ws[blk] = sD;
}

// ---------------- Kernel 2: Lg over the zs grid ----------------
__global__ __launch_bounds__(512, 4) void k_grid(const float* a, const float* b, double* ws) {
    __shared__ double2 red[8];
    __shared__ int ired[8];
    int tid = threadIdx.x, blk = blockIdx.x;
    SCf sc;
    init_scf(a, b, sc);

    // first index with dL < 0
    int cand = 1 << 30;
    #pragma unroll
    for (int j = 0; j < 2; ++j) {
        int i = tid + j * 512;
        if (ws[i] < 0.0) cand = (i < cand) ? i : cand;
    }
    int idx = block_min_int(cand, ired, tid);
    double zmax;
    if (idx >= NSCAN) zmax = 0.999;
    else if (idx == 0) zmax = 1e-3;
    else zmax = 0.5 * (scan_zs(idx - 1) + scan_zs(idx));

    PtCf p[2];
    load_points_f(tid, p);

    double t = 0.05 + (double)blk * (0.999 - 0.05) / 255.0;
    double zs = zmax * (double)(float)t;

    ItSf is;
    iter_scalars_f((float)zs, sc, is);
    float sLf = 0.0f;
    #pragma unroll
    for (int j = 0; j < 2; ++j) {
        float IL, ID;
        integrands_f<true, false>(p[j], is, sc, IL, ID);
        sLf = fmaf(p[j].wt, IL, sLf);
    }
    double sL = (double)sLf, dummy = 0.0;
    block_reduce2(sL, dummy, red, tid);
    if (tid == 0) {
        ws[WS_LG + blk] = 4.0 * zs * sL / PI_D;   // Lg
        ws[WS_ZS + blk] = zs;                     // zs_grid
    }
}

// ---------------- Kernel 3: argmin init + Newton + Vc/Vd ----------------
__global__ __launch_bounds__(512, 4) void k_newton(const float* Ls, const float* a, const float* b,
                                                   const float* logcoef, const double* ws,
                                                   float* out, int out_size, int B) {
    __shared__ double2 red[8];
    __shared__ double wv[8];
    __shared__ int wi[8];
    int tid = threadIdx.x, blk = blockIdx.x;
    SCf sc;
    init_scf(a, b, sc);

    double Lt = (double)Ls[blk];

    // argmin |Lg - L| over 256 grid entries (first-min tie-break)
    double v = (tid < NGRID) ? fabs(ws[WS_LG + tid] - Lt) : 1e300;
    int idx = (tid < NGRID) ? tid : (1 << 30);
    #pragma unroll
    for (int off = 32; off > 0; off >>= 1) {
        double ov = __shfl_xor(v, off);
        int oi = __shfl_xor(idx, off);
        if (ov < v || (ov == v && oi < idx)) { v = ov; idx = oi; }
    }
    if ((tid & 63) == 0) { wv[tid >> 6] = v; wi[tid >> 6] = idx; }
    __syncthreads();
    v = wv[0]; idx = wi[0];
    #pragma unroll
    for (int w = 1; w < 8; ++w) {
        if (wv[w] < v || (wv[w] == v && wi[w] < idx)) { v = wv[w]; idx = wi[w]; }
    }
    double zs = ws[WS_ZS + idx];
    __syncthreads();

    PtCf p[2];
    load_points_f(tid, p);

    // Newton (combined L + dL pass, f32 integrands, f64 update)
    for (int itn = 0; itn < NEWTON_ITERS; ++itn) {
        ItSf is;
        iter_scalars_f((float)zs, sc, is);
        float sLf = 0.0f, sDf = 0.0f;
        #pragma unroll
        for (int j = 0; j < 2; ++j) {
            float IL, ID;
            integrands_f<true, true>(p[j], is, sc, IL, ID);
            sLf = fmaf(p[j].wt, IL, sLf);
            sDf = fmaf(p[j].wt, ID, sDf);
        }
        double sL = (double)sLf, sD = (double)sDf;
        block_reduce2(sL, sD, red, tid);
        double L_  = 4.0 * zs * sL / PI_D;
        double dL  = sD / PI_D;
        zs = zs - (L_ - Lt) / dL;
    }

    // Vc (Y grid) + Vd (YD grid), fused; sqrt(f*g)=|bv| exactly.
    ItSf is;
    iter_scalars_f((float)zs, sc, is);
    float omzs = (float)(1.0 - zs);
    float sVcf = 0.0f, sVdf = 0.0f;
    #pragma unroll
    for (int j = 0; j < 2; ++j) {
        int k = tid + j * 512;
        bool ok = (k < NPTS);
        int kk = ok ? k : (NPTS - 1);
        {   // connected: z = zs*(1-y)(1+y)
            float u = p[j].u;
            float w2 = u * u, w4 = w2 * w2;
            float z   = is.zs * u;
            float lnz = is.lnzs + p[j].lnu;
            float z4  = is.zs4 * w4;
            float f = eval_f_f(z, lnz, z4, sc);
            float bv = eval_bv_f(z, sc);
            float inv_f = __fdividef(1.0f, f);
            float iu2 = p[j].inv_u * p[j].inv_u;
            float arg = fmaf(-w4 * is.fs, inv_f, 1.0f);   // 1 - w4*fs/f
            float Ic = fabsf(bv) * (rsqrtf(arg) - 1.0f) * p[j].y * iu2;
            sVcf = fmaf(p[j].wt, Ic, sVcf);
        }
        {   // disconnected: z = 1-(1-zs)*yd ; integrand = |bv(z)|/z^2
            float yd = (float)yYD(kk);
            float z = fmaf(-omzs, yd, 1.0f);
            float bv = eval_bv_f(z, sc);
            float Id = fabsf(bv) * __fdividef(1.0f, z * z);
            sVdf = fmaf(ok ? (float)wYD(kk) : 0.0f, Id, sVdf);
        }
    }
    double sVc = (double)sVcf, sVd = (double)sVdf;
    block_reduce2(sVc, sVd, red, tid);
    double elc = exp((double)logcoef[0]);
    double Vc = elc * PI_D * 4.0 * sVc / zs;
    double Vd = elc * PI_D * 2.0 * (1.0 - zs) * (0.5 * yYD(0) + sVd);
    double outv = Vc - Vd;

    if (tid == 0) {
        if (out_size >= 2 * B) {   // complex64 layout: interleaved re, im
            out[2 * blk]     = (float)outv;
            out[2 * blk + 1] = 0.0f;
        } else {
            out[blk] = (float)outv;
        }
    }
}

extern "C" void kernel_launch(void* const* d_in, const int* in_sizes, int n_in,
                              void* d_out, int out_size, void* d_ws, size_t ws_size,
                              hipStream_t stream) {
    const float* Ls = (const float*)d_in[0];
    const float* a  = (const float*)d_in[1];
    const float* b  = (const float*)d_in[2];
    const float* lc = (const float*)d_in[3];
    double* ws = (double*)d_ws;
    int B = in_sizes[0];

    hipLaunchKernelGGL(k_scan, dim3(NSCAN), dim3(512), 0, stream, a, b, ws);
    hipLaunchKernelGGL(k_grid, dim3(NGRID), dim3(512), 0, stream, a, b, ws);
    hipLaunchKernelGGL(k_newton, dim3(B), dim3(512), 0, stream,
                       Ls, a, b, lc, ws, (float*)d_out, out_size, B);
}

// Round 11
// 35.233 us; speedup vs baseline: 3.9394x; 1.3354x over previous
//
#include <hip/hip_runtime.h>
#include <math.h>

#define NPTS 1000
#define NGRID 256
#define NSCAN 1024
#define NEWTON_ITERS 4
#define PI_D 3.14159265358979323846

// ws layout: doubles [0..NSCAN) = scan dL; [NSCAN..NSCAN+256) = Lg;
// [NSCAN+256..NSCAN+512) = zs_grid. Float tables start at double index 1536.
#define WS_LG   NSCAN
#define WS_ZS   (NSCAN + NGRID)
#define WS_FLT  (NSCAN + 2 * NGRID)   // 1536 doubles -> float* base

// float-table offsets (in floats, from FB)
#define OF_SC   0      // 36: c[0..10], pc[11..21], bc[22..27], dbc[28..32], S=33, sa=34
#define OF_Y    36
#define OF_U    (36 + 1024)
#define OF_LNU  (36 + 2048)
#define OF_WT   (36 + 3072)
#define OF_IVU  (36 + 4096)
#define OF_YD   (36 + 5120)
#define OF_WYD  (36 + 6144)

struct SCf {
    float c[11], pc[11], bc[6], dbc[5], S, sa;
};

// f32-faithful grids (setup only, f64)
__device__ inline double yY(int k)  { return (double)(float)(1e-3 + (double)k * (0.999 - 1e-3) / 999.0); }
__device__ inline double yYD(int k) { return (double)(float)(1e-3 + (double)k * (1.0   - 1e-3) / 999.0); }

__device__ inline double wY(int k) {
    double y0 = yY(0), y1 = yY(1);
    double h = y1 - y0;
    if (k == 0)   return 0.5 * (y1 - y0) + y0 + 0.5 * y0 * y0 / h;
    if (k == 1)   return 0.5 * (yY(2) - y0) - 0.5 * y0 * y0 / h;
    if (k == 999) return 0.5 * (yY(999) - yY(998)) + 0.5 * (1.0 - yY(999));
    return 0.5 * (yY(k+1) - yY(k-1));
}
__device__ inline double wYD(int k) {
    if (k == 0)   return 0.5 * yYD(1);
    if (k == 999) return 0.5 * (yYD(999) - yYD(998));
    return 0.5 * (yYD(k+1) - yYD(k-1));
}

__device__ inline double scan_zs(int i) {
    return 1e-3 + (double)i * (0.999 - 1e-3) / (double)(NSCAN - 1);
}

// ---------------- Kernel 0: one-time f64 setup -> f32 tables ----------------
__global__ __launch_bounds__(512) void k_setup(const float* a, const float* b, double* ws) {
    float* FB = (float*)(ws + WS_FLT);
    int tid = threadIdx.x;
    if (tid == 0) {
        double _a[6], _b[6];
        _a[0] = 1.0; _b[0] = 1.0;
        for (int i = 0; i < 5; ++i) { _a[i+1] = (double)a[i]; _b[i+1] = (double)b[i]; }
        double c[11];
        for (int k = 0; k < 11; ++k) c[k] = 0.0;
        for (int i = 0; i < 6; ++i)
            for (int j = 0; j < 6; ++j)
                c[i+j] += 4.0 * _a[i] * _a[j];
        double S = 0.0;
        for (int k = 0; k < 11; ++k) {
            FB[OF_SC + k] = (float)c[k];
            double p = (k == 4) ? 0.0 : (c[k] / (double)(k - 4));
            FB[OF_SC + 11 + k] = (float)p;
            if (k != 4) S += p;
        }
        for (int i = 0; i < 6; ++i) FB[OF_SC + 22 + i] = (float)_b[i];
        for (int i = 1; i < 6; ++i) FB[OF_SC + 28 + (i-1)] = (float)((double)i * _b[i]);
        FB[OF_SC + 33] = (float)S;
        double sa = 0.0;
        for (int i = 0; i < 5; ++i) sa += (double)a[i] * (double)a[i];
        FB[OF_SC + 34] = (float)sa;
        FB[OF_SC + 35] = 0.0f;
    }
    #pragma unroll
    for (int j = 0; j < 2; ++j) {
        int k = tid + j * 512;
        int kk = (k < NPTS) ? k : (NPTS - 1);
        double y = yY(kk);
        double u = (1.0 - y) * (1.0 + y);
        FB[OF_Y   + k] = (float)y;
        FB[OF_U   + k] = (float)u;
        FB[OF_LNU + k] = (float)log(u);
        FB[OF_WT  + k] = (float)((k < NPTS) ? wY(kk) : 0.0);
        FB[OF_IVU + k] = (float)(1.0 / u);
        FB[OF_YD  + k] = (float)yYD(kk);
        FB[OF_WYD + k] = (float)((k < NPTS) ? wYD(kk) : 0.0);
    }
}

__device__ inline void load_scf(const float* FB, SCf& s) {
    #pragma unroll
    for (int k = 0; k < 11; ++k) s.c[k]  = FB[OF_SC + k];
    #pragma unroll
    for (int k = 0; k < 11; ++k) s.pc[k] = FB[OF_SC + 11 + k];
    #pragma unroll
    for (int k = 0; k < 6; ++k)  s.bc[k] = FB[OF_SC + 22 + k];
    #pragma unroll
    for (int k = 0; k < 5; ++k)  s.dbc[k] = FB[OF_SC + 28 + k];
    s.S  = FB[OF_SC + 33];
    s.sa = FB[OF_SC + 34];
}

__device__ inline float eval_f_f(float z, float lnz, float z4, const SCf& s) {
    float P = s.pc[10];
    #pragma unroll
    for (int k = 9; k >= 0; --k) P = fmaf(P, z, s.pc[k]);
    return s.S * z4 - P - s.c[4] * z4 * lnz + 0.004f * s.sa * z4 * (1.0f - z);
}
__device__ inline float eval_Q_f(float z, const SCf& s) {
    float Q = s.c[10];
    #pragma unroll
    for (int k = 9; k >= 0; --k) Q = fmaf(Q, z, s.c[k]);
    return Q;
}
__device__ inline float eval_bv_f(float z, const SCf& s) {
    float B = s.bc[5];
    #pragma unroll
    for (int k = 4; k >= 0; --k) B = fmaf(B, z, s.bc[k]);
    return B;
}
__device__ inline float eval_dbv_f(float z, const SCf& s) {
    float D = s.dbc[4];
    #pragma unroll
    for (int k = 3; k >= 0; --k) D = fmaf(D, z, s.dbc[k]);
    return D;
}

struct PtCf { float y, u, lnu, wt, inv_u; };
struct ItSf { float zs, lnzs, zs4, fs, inv_fs, inv_zs, sdf; };

__device__ inline void load_points_t(const float* FB, int tid, PtCf* p) {
    #pragma unroll
    for (int j = 0; j < 2; ++j) {
        int k = tid + j * 512;
        p[j].y     = FB[OF_Y   + k];
        p[j].u     = FB[OF_U   + k];
        p[j].lnu   = FB[OF_LNU + k];
        p[j].wt    = FB[OF_WT  + k];
        p[j].inv_u = FB[OF_IVU + k];
    }
}

__device__ inline void iter_scalars_f(float zs, const SCf& s, ItSf& it) {
    it.zs = zs;
    it.lnzs = __logf(zs);
    float z2 = zs * zs;
    it.zs4 = z2 * z2;
    it.inv_zs = __fdividef(1.0f, zs);
    float f = eval_f_f(zs, it.lnzs, it.zs4, s);
    float Q = eval_Q_f(zs, s);
    float dfs = (4.0f * f - Q) * it.inv_zs - 0.004f * s.sa * it.zs4;
    it.fs = f;
    it.inv_fs = __fdividef(1.0f, f);
    it.sdf = zs * dfs * it.inv_fs;   // zs*dfs/fs
}

// Combined L / dL integrands (f32). sqrt(1-z/zs)=y; 1/(Am1^1.5)=rsqrt^3.
template <bool NL, bool ND>
__device__ inline void integrands_f(const PtCf& p, const ItSf& is, const SCf& s,
                                    float& IL, float& ID) {
    float u = p.u;
    float w2 = u * u, w4 = w2 * w2;
    float z   = is.zs * u;
    float lnz = is.lnzs + p.lnu;
    float z4  = is.zs4 * w4;
    float f = eval_f_f(z, lnz, z4, s);
    float bv = eval_bv_f(z, s);
    float inv_f = __fdividef(1.0f, f);
    float sqrtg = fabsf(bv) * rsqrtf(f);
    float fofs = f * is.inv_fs;
    float iu2 = p.inv_u * p.inv_u;
    float r4 = iu2 * iu2;                // zs^4/z^4
    float A = fofs * r4;
    float r = rsqrtf(A - 1.0f);
    if (NL) {
        IL = sqrtg * p.y * r;
    }
    if (ND) {
        float Q = eval_Q_f(z, s);
        float inv_z = is.inv_zs * p.inv_u;
        float df = (4.0f * f - Q) * inv_z - 0.004f * s.sa * z4;
        float dbv = eval_dbv_f(z, s);
        float t = z * (2.0f * __fdividef(dbv, bv) - df * inv_f);   // z*dg/g
        float i1 = A * (is.sdf + 2.0f + t) - r4 * z * df * is.inv_fs - 2.0f - t;
        ID = i1 * 2.0f * p.y * sqrtg * (r * r * r);
    }
}

// deterministic block reductions (512 threads = 8 waves)
__device__ inline void block_reduce2(double& sx, double& sy, double2* lds, int tid) {
    #pragma unroll
    for (int off = 32; off > 0; off >>= 1) {
        sx += __shfl_xor(sx, off);
        sy += __shfl_xor(sy, off);
    }
    int wid = tid >> 6;
    if ((tid & 63) == 0) lds[wid] = make_double2(sx, sy);
    __syncthreads();
    double rx = 0.0, ry = 0.0;
    #pragma unroll
    for (int w = 0; w < 8; ++w) { rx += lds[w].x; ry += lds[w].y; }
    __syncthreads();
    sx = rx; sy = ry;
}
__device__ inline double block_reduce1(double sx, double* lds, int tid) {
    #pragma unroll
    for (int off = 32; off > 0; off >>= 1) sx += __shfl_xor(sx, off);
    if ((tid & 63) == 0) lds[tid >> 6] = sx;
    __syncthreads();
    double rx = 0.0;
    #pragma unroll
    for (int w = 0; w < 8; ++w) rx += lds[w];
    __syncthreads();
    return rx;
}
__device__ inline int block_min_int(int v, int* lds, int tid) {
    #pragma unroll
    for (int off = 32; off > 0; off >>= 1) {
        int o = __shfl_xor(v, off);
        v = (o < v) ? o : v;
    }
    if ((tid & 63) == 0) lds[tid >> 6] = v;
    __syncthreads();
    int r = lds[0];
    #pragma unroll
    for (int w = 1; w < 8; ++w) r = (lds[w] < r) ? lds[w] : r;
    __syncthreads();
    return r;
}

// ---------------- Kernel 1: parallel dL sign-scan ----------------
__global__ __launch_bounds__(512, 4) void k_scan(double* ws) {
    __shared__ double red[8];
    const float* FB = (const float*)(ws + WS_FLT);
    int tid = threadIdx.x, blk = blockIdx.x;
    SCf sc;
    load_scf(FB, sc);
    PtCf p[2];
    load_points_t(FB, tid, p);

    ItSf is;
    iter_scalars_f((float)scan_zs(blk), sc, is);
    float sDf = 0.0f;
    #pragma unroll
    for (int j = 0; j < 2; ++j) {
        float IL, ID;
        integrands_f<false, true>(p[j], is, sc, IL, ID);
        sDf = fmaf(p[j].wt, ID, sDf);
    }
    double sD = block_reduce1((double)sDf, red, tid);
    if (tid == 0) ws[blk] = sD;
}

// ---------------- Kernel 2: Lg over the zs grid ----------------
__global__ __launch_bounds__(512, 4) void k_grid(double* ws) {
    __shared__ double red[8];
    __shared__ int ired[8];
    const float* FB = (const float*)(ws + WS_FLT);
    int tid = threadIdx.x, blk = blockIdx.x;
    SCf sc;
    load_scf(FB, sc);

    // first index with dL < 0
    int cand = 1 << 30;
    #pragma unroll
    for (int j = 0; j < 2; ++j) {
        int i = tid + j * 512;
        if (ws[i] < 0.0) cand = (i < cand) ? i : cand;
    }
    int idx = block_min_int(cand, ired, tid);
    double zmax;
    if (idx >= NSCAN) zmax = 0.999;
    else if (idx == 0) zmax = 1e-3;
    else zmax = 0.5 * (scan_zs(idx - 1) + scan_zs(idx));

    PtCf p[2];
    load_points_t(FB, tid, p);

    double t = 0.05 + (double)blk * (0.999 - 0.05) / 255.0;
    double zs = zmax * (double)(float)t;

    ItSf is;
    iter_scalars_f((float)zs, sc, is);
    float sLf = 0.0f;
    #pragma unroll
    for (int j = 0; j < 2; ++j) {
        float IL, ID;
        integrands_f<true, false>(p[j], is, sc, IL, ID);
        sLf = fmaf(p[j].wt, IL, sLf);
    }
    double sL = block_reduce1((double)sLf, red, tid);
    if (tid == 0) {
        ws[WS_LG + blk] = 4.0 * zs * sL / PI_D;   // Lg
        ws[WS_ZS + blk] = zs;                     // zs_grid
    }
}

// ---------------- Kernel 3: argmin init + Newton + Vc/Vd ----------------
__global__ __launch_bounds__(512, 4) void k_newton(const float* Ls, const float* logcoef,
                                                   const double* ws, float* out,
                                                   int out_size, int B) {
    __shared__ double2 red[8];
    __shared__ double wv[8];
    __shared__ int wi[8];
    const float* FB = (const float*)(ws + WS_FLT);
    int tid = threadIdx.x, blk = blockIdx.x;
    SCf sc;
    load_scf(FB, sc);

    double Lt = (double)Ls[blk];

    // argmin |Lg - L| over 256 grid entries (first-min tie-break)
    double v = (tid < NGRID) ? fabs(ws[WS_LG + tid] - Lt) : 1e300;
    int idx = (tid < NGRID) ? tid : (1 << 30);
    #pragma unroll
    for (int off = 32; off > 0; off >>= 1) {
        double ov = __shfl_xor(v, off);
        int oi = __shfl_xor(idx, off);
        if (ov < v || (ov == v && oi < idx)) { v = ov; idx = oi; }
    }
    if ((tid & 63) == 0) { wv[tid >> 6] = v; wi[tid >> 6] = idx; }
    __syncthreads();
    v = wv[0]; idx = wi[0];
    #pragma unroll
    for (int w = 1; w < 8; ++w) {
        if (wv[w] < v || (wv[w] == v && wi[w] < idx)) { v = wv[w]; idx = wi[w]; }
    }
    double zs = ws[WS_ZS + idx];
    __syncthreads();

    PtCf p[2];
    load_points_t(FB, tid, p);

    // Newton (combined L + dL pass, f32 integrands, f64 update)
    for (int itn = 0; itn < NEWTON_ITERS; ++itn) {
        ItSf is;
        iter_scalars_f((float)zs, sc, is);
        float sLf = 0.0f, sDf = 0.0f;
        #pragma unroll
        for (int j = 0; j < 2; ++j) {
            float IL, ID;
            integrands_f<true, true>(p[j], is, sc, IL, ID);
            sLf = fmaf(p[j].wt, IL, sLf);
            sDf = fmaf(p[j].wt, ID, sDf);
        }
        double sL = (double)sLf, sD = (double)sDf;
        block_reduce2(sL, sD, red, tid);
        double L_  = 4.0 * zs * sL / PI_D;
        double dL  = sD / PI_D;
        zs = zs - (L_ - Lt) / dL;
    }

    // Vc (Y grid) + Vd (YD grid), fused; sqrt(f*g)=|bv| exactly.
    ItSf is;
    iter_scalars_f((float)zs, sc, is);
    float omzs = (float)(1.0 - zs);
    float sVcf = 0.0f, sVdf = 0.0f;
    #pragma unroll
    for (int j = 0; j < 2; ++j) {
        int k = tid + j * 512;
        {   // connected: z = zs*(1-y)(1+y)
            float u = p[j].u;
            float w2 = u * u, w4 = w2 * w2;
            float z   = is.zs * u;
            float lnz = is.lnzs + p[j].lnu;
            float z4  = is.zs4 * w4;
            float f = eval_f_f(z, lnz, z4, sc);
            float bv = eval_bv_f(z, sc);
            float inv_f = __fdividef(1.0f, f);
            float iu2 = p[j].inv_u * p[j].inv_u;
            float arg = fmaf(-w4 * is.fs, inv_f, 1.0f);   // 1 - w4*fs/f
            float Ic = fabsf(bv) * (rsqrtf(arg) - 1.0f) * p[j].y * iu2;
            sVcf = fmaf(p[j].wt, Ic, sVcf);
        }
        {   // disconnected: z = 1-(1-zs)*yd ; integrand = |bv(z)|/z^2
            float yd = FB[OF_YD + k];
            float wyd = FB[OF_WYD + k];
            float z = fmaf(-omzs, yd, 1.0f);
            float bv = eval_bv_f(z, sc);
            float Id = fabsf(bv) * __fdividef(1.0f, z * z);
            sVdf = fmaf(wyd, Id, sVdf);
        }
    }
    double sVc = (double)sVcf, sVd = (double)sVdf;
    block_reduce2(sVc, sVd, red, tid);
    double elc = exp((double)logcoef[0]);
    double Vc = elc * PI_D * 4.0 * sVc / zs;
    double Vd = elc * PI_D * 2.0 * (1.0 - zs) * (0.5 * yYD(0) + sVd);
    double outv = Vc - Vd;

    if (tid == 0) {
        if (out_size >= 2 * B) {   // complex64 layout: interleaved re, im
            out[2 * blk]     = (float)outv;
            out[2 * blk + 1] = 0.0f;
        } else {
            out[blk] = (float)outv;
        }
    }
}

extern "C" void kernel_launch(void* const* d_in, const int* in_sizes, int n_in,
                              void* d_out, int out_size, void* d_ws, size_t ws_size,
                              hipStream_t stream) {
    const float* Ls = (const float*)d_in[0];
    const float* a  = (const float*)d_in[1];
    const float* b  = (const float*)d_in[2];
    const float* lc = (const float*)d_in[3];
    double* ws = (double*)d_ws;
    int B = in_sizes[0];

    hipLaunchKernelGGL(k_setup, dim3(1), dim3(512), 0, stream, a, b, ws);
    hipLaunchKernelGGL(k_scan, dim3(NSCAN), dim3(512), 0, stream, ws);
    hipLaunchKernelGGL(k_grid, dim3(NGRID), dim3(512), 0, stream, ws);
    hipLaunchKernelGGL(k_newton, dim3(B), dim3(512), 0, stream,
                       Ls, lc, ws, (float*)d_out, out_size, B);
}

// Round 12
// 23.546 us; speedup vs baseline: 5.8947x; 1.4964x over previous
//
#include <hip/hip_runtime.h>
#include <math.h>

#define NPTS 1000
#define NGRID 256
#define NEWTON_ITERS 3
#define PI_D 3.14159265358979323846

// Y grid: linspace(1e-3, 0.999, 1000). YD grid: linspace(1e-3, 1.0, 1000).
#define HY   ((0.999 - 1e-3) / 999.0)
#define Y0C  (1e-3)
#define HD   ((1.0 - 1e-3) / 999.0)

// trapz+extrapolation weights (closed form — uniform grid)
#define WY0   (0.5 * HY + Y0C + 0.5 * Y0C * Y0C / HY)
#define WY1   (HY - 0.5 * Y0C * Y0C / HY)
#define WY999 (0.5 * HY + 0.5 * (1.0 - 0.999))
#define WD0   (0.5 * (Y0C + HD))
#define WD999 (0.5 * HD)

struct SCf {
    float c[11], pc[11], bc[6], dbc[5], S, sa;
};

// Per-thread f32 coefficient folding (~70 FLOPs, all-register).
__device__ inline void make_scf(const float* a, const float* b, SCf& s) {
    float af[6], bf[6];
    af[0] = 1.0f; bf[0] = 1.0f;
    #pragma unroll
    for (int i = 0; i < 5; ++i) { af[i+1] = a[i]; bf[i+1] = b[i]; }
    #pragma unroll
    for (int k = 0; k < 11; ++k) s.c[k] = 0.0f;
    #pragma unroll
    for (int i = 0; i < 6; ++i)
        #pragma unroll
        for (int j = 0; j < 6; ++j)
            s.c[i+j] = fmaf(4.0f * af[i], af[j], s.c[i+j]);
    const float INVK[11] = { -0.25f, -1.0f/3.0f, -0.5f, -1.0f, 0.0f,
                              1.0f, 0.5f, 1.0f/3.0f, 0.25f, 0.2f, 1.0f/6.0f };
    float S = 0.0f;
    #pragma unroll
    for (int k = 0; k < 11; ++k) { s.pc[k] = s.c[k] * INVK[k]; S += s.pc[k]; }
    s.S = S;
    float sa = 0.0f;
    #pragma unroll
    for (int i = 0; i < 5; ++i) sa = fmaf(a[i], a[i], sa);
    s.sa = sa;
    #pragma unroll
    for (int i = 0; i < 6; ++i) s.bc[i] = bf[i];
    #pragma unroll
    for (int i = 1; i < 6; ++i) s.dbc[i-1] = (float)i * bf[i];
}

__device__ inline float eval_f_f(float z, float lnz, float z4, const SCf& s) {
    float P = s.pc[10];
    #pragma unroll
    for (int k = 9; k >= 0; --k) P = fmaf(P, z, s.pc[k]);
    return s.S * z4 - P - s.c[4] * z4 * lnz + 0.004f * s.sa * z4 * (1.0f - z);
}
__device__ inline float eval_Q_f(float z, const SCf& s) {
    float Q = s.c[10];
    #pragma unroll
    for (int k = 9; k >= 0; --k) Q = fmaf(Q, z, s.c[k]);
    return Q;
}
__device__ inline float eval_bv_f(float z, const SCf& s) {
    float B = s.bc[5];
    #pragma unroll
    for (int k = 4; k >= 0; --k) B = fmaf(B, z, s.bc[k]);
    return B;
}
__device__ inline float eval_dbv_f(float z, const SCf& s) {
    float D = s.dbc[4];
    #pragma unroll
    for (int k = 3; k >= 0; --k) D = fmaf(D, z, s.dbc[k]);
    return D;
}

struct PtCf { float y, u, lnu, wt, inv_u; };
struct ItSf { float zs, lnzs, zs4, fs, inv_fs, inv_zs, sdf; };

// Per-thread point constants (f32 hot ops; y from f64 fma for grid fidelity).
__device__ inline void make_points(int tid, PtCf* p) {
    #pragma unroll
    for (int j = 0; j < 2; ++j) {
        int k = tid + j * 512;
        int kk = (k < NPTS) ? k : (NPTS - 1);
        float y = (float)(Y0C + (double)kk * HY);
        float u = (1.0f - y) * (1.0f + y);
        p[j].y = y;
        p[j].u = u;
        p[j].lnu = __logf(u);
        p[j].inv_u = __fdividef(1.0f, u);
        float wt;
        if (k >= NPTS)      wt = 0.0f;
        else if (k == 0)    wt = (float)WY0;
        else if (k == 1)    wt = (float)WY1;
        else if (k == 999)  wt = (float)WY999;
        else                wt = (float)HY;
        p[j].wt = wt;
    }
}

__device__ inline void iter_scalars_f(float zs, const SCf& s, ItSf& it) {
    it.zs = zs;
    it.lnzs = __logf(zs);
    float z2 = zs * zs;
    it.zs4 = z2 * z2;
    it.inv_zs = __fdividef(1.0f, zs);
    float f = eval_f_f(zs, it.lnzs, it.zs4, s);
    float Q = eval_Q_f(zs, s);
    float dfs = (4.0f * f - Q) * it.inv_zs - 0.004f * s.sa * it.zs4;
    it.fs = f;
    it.inv_fs = __fdividef(1.0f, f);
    it.sdf = zs * dfs * it.inv_fs;   // zs*dfs/fs
}

// Combined L / dL integrands (f32). sqrt(1-z/zs)=y; 1/(Am1^1.5)=rsqrt^3.
template <bool NL, bool ND>
__device__ inline void integrands_f(const PtCf& p, const ItSf& is, const SCf& s,
                                    float& IL, float& ID) {
    float u = p.u;
    float w2 = u * u, w4 = w2 * w2;
    float z   = is.zs * u;
    float lnz = is.lnzs + p.lnu;
    float z4  = is.zs4 * w4;
    float f = eval_f_f(z, lnz, z4, s);
    float bv = eval_bv_f(z, s);
    float inv_f = __fdividef(1.0f, f);
    float sqrtg = fabsf(bv) * rsqrtf(f);
    float fofs = f * is.inv_fs;
    float iu2 = p.inv_u * p.inv_u;
    float r4 = iu2 * iu2;                // zs^4/z^4
    float A = fofs * r4;
    float r = rsqrtf(A - 1.0f);
    if (NL) {
        IL = sqrtg * p.y * r;
    }
    if (ND) {
        float Q = eval_Q_f(z, s);
        float inv_z = is.inv_zs * p.inv_u;
        float df = (4.0f * f - Q) * inv_z - 0.004f * s.sa * z4;
        float dbv = eval_dbv_f(z, s);
        float t = z * (2.0f * __fdividef(dbv, bv) - df * inv_f);   // z*dg/g
        float i1 = A * (is.sdf + 2.0f + t) - r4 * z * df * is.inv_fs - 2.0f - t;
        ID = i1 * 2.0f * p.y * sqrtg * (r * r * r);
    }
}

// deterministic block reduction of 2 doubles (512 threads = 8 waves)
__device__ inline void block_reduce2(double& sx, double& sy, double2* lds, int tid) {
    #pragma unroll
    for (int off = 32; off > 0; off >>= 1) {
        sx += __shfl_xor(sx, off);
        sy += __shfl_xor(sy, off);
    }
    int wid = tid >> 6;
    if ((tid & 63) == 0) lds[wid] = make_double2(sx, sy);
    __syncthreads();
    double rx = 0.0, ry = 0.0;
    #pragma unroll
    for (int w = 0; w < 8; ++w) { rx += lds[w].x; ry += lds[w].y; }
    __syncthreads();
    sx = rx; sy = ry;
}

__device__ inline double grid_zs(int i) {
    return 0.05 + (double)i * (0.999 - 0.05) / 255.0;
}

// ---- Kernel 1: Lg (masked to rising branch) over a FIXED zs grid ----
__global__ __launch_bounds__(512, 4) void k_grid(const float* a, const float* b, float* W) {
    __shared__ double2 red[8];
    int tid = threadIdx.x, blk = blockIdx.x;
    SCf sc;
    make_scf(a, b, sc);
    PtCf p[2];
    make_points(tid, p);

    float zs = (float)grid_zs(blk);
    ItSf is;
    iter_scalars_f(zs, sc, is);
    float sLf = 0.0f, sDf = 0.0f;
    #pragma unroll
    for (int j = 0; j < 2; ++j) {
        float IL, ID;
        integrands_f<true, true>(p[j], is, sc, IL, ID);
        sLf = fmaf(p[j].wt, IL, sLf);
        sDf = fmaf(p[j].wt, ID, sDf);
    }
    double sL = (double)sLf, sD = (double)sDf;
    block_reduce2(sL, sD, red, tid);
    if (tid == 0) {
        // mask non-rising-branch candidates (dL <= 0)
        W[blk] = (sD > 0.0) ? (float)(4.0 * (double)zs * sL / PI_D) : 1e30f;
    }
}

// ---- Kernel 2: argmin init + Newton + Vc/Vd ----
__global__ __launch_bounds__(512, 4) void k_newton(const float* Ls, const float* a,
                                                   const float* b, const float* logcoef,
                                                   const float* W, float* out,
                                                   int out_size, int B) {
    __shared__ double2 red[8];
    __shared__ float wv[8];
    __shared__ int wi[8];
    int tid = threadIdx.x, blk = blockIdx.x;
    SCf sc;
    make_scf(a, b, sc);

    float Ltf = Ls[blk];
    double Lt = (double)Ltf;

    // argmin |Lg - L| over 256 masked entries (first-min tie-break)
    float v = (tid < NGRID) ? fabsf(W[tid] - Ltf) : 3e38f;
    int idx = (tid < NGRID) ? tid : (1 << 30);
    #pragma unroll
    for (int off = 32; off > 0; off >>= 1) {
        float ov = __shfl_xor(v, off);
        int oi = __shfl_xor(idx, off);
        if (ov < v || (ov == v && oi < idx)) { v = ov; idx = oi; }
    }
    if ((tid & 63) == 0) { wv[tid >> 6] = v; wi[tid >> 6] = idx; }
    __syncthreads();
    v = wv[0]; idx = wi[0];
    #pragma unroll
    for (int w = 1; w < 8; ++w) {
        if (wv[w] < v || (wv[w] == v && wi[w] < idx)) { v = wv[w]; idx = wi[w]; }
    }
    double zs = grid_zs(idx);

    PtCf p[2];
    make_points(tid, p);

    // Newton (combined L + dL pass; f32 integrands, f64 update)
    for (int itn = 0; itn < NEWTON_ITERS; ++itn) {
        ItSf is;
        iter_scalars_f((float)zs, sc, is);
        float sLf = 0.0f, sDf = 0.0f;
        #pragma unroll
        for (int j = 0; j < 2; ++j) {
            float IL, ID;
            integrands_f<true, true>(p[j], is, sc, IL, ID);
            sLf = fmaf(p[j].wt, IL, sLf);
            sDf = fmaf(p[j].wt, ID, sDf);
        }
        double sL = (double)sLf, sD = (double)sDf;
        block_reduce2(sL, sD, red, tid);
        double L_  = 4.0 * zs * sL / PI_D;
        double dL  = sD / PI_D;
        zs = zs - (L_ - Lt) / dL;
        zs = fmin(fmax(zs, 1e-3), 0.999);   // domain clamp (no-op at convergence)
    }

    // Vc (Y grid) + Vd (YD grid), fused; sqrt(f*g)=|bv| exactly.
    ItSf is;
    iter_scalars_f((float)zs, sc, is);
    float omzs = (float)(1.0 - zs);
    float sVcf = 0.0f, sVdf = 0.0f;
    #pragma unroll
    for (int j = 0; j < 2; ++j) {
        int k = tid + j * 512;
        int kk = (k < NPTS) ? k : (NPTS - 1);
        {   // connected: z = zs*(1-y)(1+y)
            float u = p[j].u;
            float w2 = u * u, w4 = w2 * w2;
            float z   = is.zs * u;
            float lnz = is.lnzs + p[j].lnu;
            float z4  = is.zs4 * w4;
            float f = eval_f_f(z, lnz, z4, sc);
            float bv = eval_bv_f(z, sc);
            float inv_f = __fdividef(1.0f, f);
            float iu2 = p[j].inv_u * p[j].inv_u;
            float arg = fmaf(-w4 * is.fs, inv_f, 1.0f);   // 1 - w4*fs/f
            float Ic = fabsf(bv) * (rsqrtf(arg) - 1.0f) * p[j].y * iu2;
            sVcf = fmaf(p[j].wt, Ic, sVcf);
        }
        {   // disconnected: z = 1-(1-zs)*yd ; integrand = |bv(z)|/z^2
            float yd = (float)(Y0C + (double)kk * HD);
            float wyd;
            if (k >= NPTS)      wyd = 0.0f;
            else if (k == 0)    wyd = (float)WD0;
            else if (k == 999)  wyd = (float)WD999;
            else                wyd = (float)HD;
            float z = fmaf(-omzs, yd, 1.0f);
            float bv = eval_bv_f(z, sc);
            float Id = fabsf(bv) * __fdividef(1.0f, z * z);
            sVdf = fmaf(wyd, Id, sVdf);
        }
    }
    double sVc = (double)sVcf, sVd = (double)sVdf;
    block_reduce2(sVc, sVd, red, tid);
    double elc = exp((double)logcoef[0]);
    double Vc = elc * PI_D * 4.0 * sVc / zs;
    double Vd = elc * PI_D * 2.0 * (1.0 - zs) * (0.5 * Y0C + sVd);
    double outv = Vc - Vd;

    if (tid == 0) {
        if (out_size >= 2 * B) {   // complex64 layout: interleaved re, im
            out[2 * blk]     = (float)outv;
            out[2 * blk + 1] = 0.0f;
        } else {
            out[blk] = (float)outv;
        }
    }
}

extern "C" void kernel_launch(void* const* d_in, const int* in_sizes, int n_in,
                              void* d_out, int out_size, void* d_ws, size_t ws_size,
                              hipStream_t stream) {
    const float* Ls = (const float*)d_in[0];
    const float* a  = (const float*)d_in[1];
    const float* b  = (const float*)d_in[2];
    const float* lc = (const float*)d_in[3];
    float* W = (float*)d_ws;
    int B = in_sizes[0];

    hipLaunchKernelGGL(k_grid, dim3(NGRID), dim3(512), 0, stream, a, b, W);
    hipLaunchKernelGGL(k_newton, dim3(B), dim3(512), 0, stream,
                       Ls, a, b, lc, W, (float*)d_out, out_size, B);
}